// Round 3
// baseline (383.984 us; speedup 1.0000x reference)
//
#include <hip/hip_runtime.h>
#include <cstdint>

typedef unsigned short u16;
typedef __attribute__((ext_vector_type(4))) int i32x4;

#define DEVI __device__ __forceinline__

// ---- float32 replication of reference ops (np ref computes in f32) ---------
DEVI float pactf(float x, float a) {             // literal op order, f32 CR
    float ax = fabsf(x);
    float w  = fabsf(ax - a);
    float t  = (ax - w) + a;
    float s  = (x > 0.f) ? 0.5f : ((x < 0.f) ? -0.5f : 0.0f);
    return s * t;
}
DEVI float quantf(float x, float r) {            // quant_raw value path, f32
    float xs = x / r;
    xs = fminf(fmaxf(xs, -0.9921875f), 0.9921875f);
    float e = rintf(xs * 128.0f);                // round half-even, exact
    return (e * 0.0078125f) * r;                 // e/128 exact pow2
}
// f32 transcendentals replicated via correctly-rounded f64 -> f32 rounding
// (matches numpy/glibc CR expf/tanhf to the bit; OCML f32 expf is ~1 ulp off)
DEVI float sigf(float x) {
    float eg  = (float)exp(-(double)x);          // CR f32 exp(-x)
    float den = 1.0f + eg;                       // f32 add CR
    return 1.0f / den;                           // f32 div CR
}
DEVI float tanf32(float x) { return (float)tanh((double)x); }

// ---- prep: bitsplit activations in FLOAT32 -> int8 planes, char4-packed ----
__global__ void prep_act_f(const float* __restrict__ X, const float* __restrict__ ap,
                           signed char* __restrict__ A, int planebase) {
    int idx4 = (blockIdx.x * 256 + threadIdx.x) * 4;   // 0..4194300 step 4
    float a = ap[0];
    float4 xv4 = *(const float4*)(X + idx4);
    float v[4] = {xv4.x, xv4.y, xv4.z, xv4.w};
    signed char e4[4][4];                        // [n][elem]
#pragma unroll
    for (int el = 0; el < 4; el++) {
        float x = pactf(v[el], a) / a;           // f32 division, CR
        float xv = x;
        float beta = 1.0f;
#pragma unroll
        for (int n = 0; n < 4; n++) {
            float xs = xv / beta;                // pow2: exact
            xs = fminf(fmaxf(xs, -0.9921875f), 0.9921875f);
            float e = rintf(xs * 128.0f);        // integer in [-127,127]
            e4[n][el] = (signed char)(int)e;
            float y = e * 0.0078125f;            // e/128 exact
            xv = xv - y * beta;                  // f32 CR (product exact)
            beta = beta * 0.5f;
        }
    }
#pragma unroll
    for (int n = 0; n < 4; n++)
        *(char4*)(A + (size_t)(planebase + n) * 4194304u + idx4) =
            make_char4(e4[n][0], e4[n][1], e4[n][2], e4[n][3]);
}

// ---- prep: quantize + transpose weights -> Wt[proj][n=4096][k=1024] int8 ---
__global__ void prep_w(const float* __restrict__ W0, const float* __restrict__ W1,
                       signed char* __restrict__ Wt) {
    __shared__ float tile[32][33];
    int proj = blockIdx.z;
    const float* W = proj ? W1 : W0;             // [1024][4096] row-major
    int n0 = blockIdx.x * 32, k0 = blockIdx.y * 32;
    int tx = threadIdx.x, ty = threadIdx.y;
#pragma unroll
    for (int i = 0; i < 4; i++)
        tile[ty + i * 8][tx] = W[(size_t)(k0 + ty + i * 8) * 4096 + n0 + tx];
    __syncthreads();
#pragma unroll
    for (int i = 0; i < 4; i++) {
        float w = tile[tx][ty + i * 8];
        float xs = fminf(fmaxf(w, -0.9921875f), 0.9921875f);
        float e = rintf(xs * 128.f);             // Wq*128 integer, exact
        Wt[(size_t)proj * 4194304u + (size_t)(n0 + ty + i * 8) * 1024 + k0 + tx] =
            (signed char)(int)e;
    }
}

// ---- prep: bias integers (exact) -------------------------------------------
__global__ void prep_bias(const float* __restrict__ b0, const float* __restrict__ b1,
                          float* __restrict__ Bf) {
    int idx = blockIdx.x * 256 + threadIdx.x;    // 0..8191
    const float* b = (idx < 4096) ? b0 : b1;
    float v = b[idx & 4095];
    float xs = fminf(fmaxf(v, -0.9921875f), 0.9921875f);
    Bf[idx] = rintf(xs * 128.f);
}

// ---- main GEMM: int8 MFMA, exact i32 accumulation --------------------------
// A rows: (proj*4 + n)*4096 + b, K=1024 int8. Wt[proj][n][k] int8.
// e = rndne(clip(S/128 + Bint, +-127)) — exact float path (|t|*128 < 2^24).
#define GLOAD16(gp, lp) __builtin_amdgcn_global_load_lds( \
    (const __attribute__((address_space(1))) void*)(gp),  \
    (__attribute__((address_space(3))) void*)(lp), 16, 0, 0)

__global__ __launch_bounds__(256) void gemm_planes(
    const signed char* __restrict__ A, const signed char* __restrict__ Wt,
    const float* __restrict__ Bf, signed char* __restrict__ E) {
    __shared__ __align__(16) signed char lds[16384]; // A tile 8KB | B tile 8KB
    int tid = threadIdx.x;
    int c0 = blockIdx.x * 128;                   // N (gate cols 0..4095)
    int r0 = blockIdx.y * 128;                   // stacked M
    int proj = (r0 >= 16384) ? 1 : 0;

    const signed char* gA = A + (size_t)(r0 + (tid >> 2)) * 1024 + (tid & 3) * 16;
    const signed char* gB = Wt + (size_t)proj * 4194304u + (size_t)(c0 + (tid >> 2)) * 1024 + (tid & 3) * 16;

    signed char* lA0 = lds + tid * 16;           // A rows 0..63
    signed char* lA1 = lds + 4096 + tid * 16;    // A rows 64..127
    signed char* lB0 = lds + 8192 + tid * 16;
    signed char* lB1 = lds + 12288 + tid * 16;

    int w = tid >> 6, l = tid & 63;
    int wm = (w >> 1) * 64, wn = (w & 1) * 64;   // wave quadrant, 64x64
    int quad = l >> 4, lrow = l & 15;

    const signed char* fA = lds + (wm + lrow) * 64 + quad * 16;
    const signed char* fB = lds + 8192 + (wn + lrow) * 64 + quad * 16;

    i32x4 acc[4][4] = {};

    for (int k0 = 0; k0 < 1024; k0 += 64) {      // 16 iterations
        GLOAD16(gA, lA0);
        GLOAD16(gA + 64 * 1024, lA1);
        GLOAD16(gB, lB0);
        GLOAD16(gB + 64 * 1024, lB1);
        gA += 64; gB += 64;
        asm volatile("s_waitcnt vmcnt(0)" ::: "memory");
        __syncthreads();
        i32x4 af[4], bfr[4];
#pragma unroll
        for (int mt = 0; mt < 4; mt++) af[mt] = *(const i32x4*)(fA + mt * 1024);
#pragma unroll
        for (int nt = 0; nt < 4; nt++) bfr[nt] = *(const i32x4*)(fB + nt * 1024);
#pragma unroll
        for (int mt = 0; mt < 4; mt++)
#pragma unroll
            for (int nt = 0; nt < 4; nt++)
                acc[mt][nt] = __builtin_amdgcn_mfma_i32_16x16x64_i8(
                    af[mt], bfr[nt], acc[mt][nt], 0, 0, 0);
        __syncthreads();
    }

    // Epilogue: int8 via LDS transpose so stores are h-contiguous coalesced.
    signed char* ctile = lds;                    // 128x128 bytes
#pragma unroll
    for (int nt = 0; nt < 4; nt++) {
        int lc = wn + nt * 16 + lrow;            // col = lane&15
        float bb = Bf[proj * 4096 + c0 + lc];
#pragma unroll
        for (int mt = 0; mt < 4; mt++) {
            int lr = wm + mt * 16 + quad * 4;    // row = quad*4+reg
#pragma unroll
            for (int r = 0; r < 4; r++) {
                float t = (float)acc[mt][nt][r] * 0.0078125f + bb;  // exact
                float tc = fminf(fmaxf(t, -127.f), 127.f);
                ctile[(lr + r) * 128 + lc] = (signed char)(int)rintf(tc);
            }
        }
    }
    __syncthreads();
#pragma unroll
    for (int p = 0; p < 4; p++) {
        int lr = (tid >> 3) + p * 32;
        int lc = (tid & 7) * 16;
        *(int4*)(E + (size_t)(r0 + lr) * 4096 + c0 + lc) =
            *(const int4*)(ctile + lr * 128 + lc);
    }
}

// ---- gates: reassemble (exact f64) + elementwise chain in FLOAT32 ----------
// OUTPUT IS FLOAT32 [2][4096][1024].
__global__ void gates_kernel_f(const signed char* __restrict__ E,
                               const float* __restrict__ cx, float* __restrict__ out,
                               const float* __restrict__ a1p, const float* __restrict__ a3p,
                               const float* __restrict__ a4p, const float* __restrict__ a5p,
                               const float* __restrict__ a6p, const float* __restrict__ a7p,
                               const float* __restrict__ a8p, const float* __restrict__ a9p,
                               const float* __restrict__ a10p, const float* __restrict__ a11p) {
    int b = blockIdx.x;
    int h0 = threadIdx.x * 4;                    // 4 h per thread
    double a1 = (double)a1p[0], a11d = (double)a11p[0];
    float a3 = a3p[0], a4 = a4p[0], a5 = a5p[0], a6 = a6p[0], a7 = a7p[0];
    float a8 = a8p[0], a9 = a9p[0], a10 = a10p[0], a11 = a11p[0];
    const double betav[4] = {1.0, 0.5, 0.25, 0.125};

    float gate[4][4];                            // [i,j,f,o][h-sub]
#pragma unroll
    for (int g = 0; g < 4; g++) {
        size_t colbase = (size_t)g * 1024 + h0;
        double s1[4] = {0, 0, 0, 0}, s2[4] = {0, 0, 0, 0};
#pragma unroll
        for (int n = 0; n < 4; n++) {
            char4 e1 = *(const char4*)(E + (((size_t)(n * 4096 + b)) << 12) + colbase);
            char4 e2 = *(const char4*)(E + (((size_t)((4 + n) * 4096 + b)) << 12) + colbase);
            double bt = betav[n];
            s1[0] += bt * (double)e1.x; s1[1] += bt * (double)e1.y;
            s1[2] += bt * (double)e1.z; s1[3] += bt * (double)e1.w;
            s2[0] += bt * (double)e2.x; s2[1] += bt * (double)e2.y;
            s2[2] += bt * (double)e2.z; s2[3] += bt * (double)e2.w;
        }
#pragma unroll
        for (int jj = 0; jj < 4; jj++)           // exact: ints scaled by pow2;
            gate[g][jj] = (float)((s1[jj] / 128.0) * a1 + (s2[jj] / 128.0) * a11d);
    }

    float4 cxv = *(const float4*)(cx + (size_t)b * 1024 + h0);
    float cxa[4] = {cxv.x, cxv.y, cxv.z, cxv.w};
    float nh[4], ncv[4];
#pragma unroll
    for (int jj = 0; jj < 4; jj++) {
        float gi = gate[0][jj], gj = gate[1][jj], gf = gate[2][jj], go = gate[3][jj];
        float fg  = quantf(pactf(sigf(gf), a3), a3);
        float ig  = quantf(pactf(sigf(gi), a4), a4);
        float act = quantf(pactf(tanf32(gj), a5), a5);
        float og  = quantf(pactf(sigf(go), a6), a6);
        float gc  = quantf(pactf(cxa[jj] * fg, a7), a7);
        float ai  = quantf(pactf(ig * act, a8), a8);
        float nc  = quantf(pactf(gc + ai, a9), a9);
        float ac  = quantf(pactf(tanf32(nc), a10), a10);
        float hh  = quantf(pactf(ac * og, a11), a11);
        nh[jj]  = hh;
        ncv[jj] = nc;
    }
    float4 o1 = {nh[0], nh[1], nh[2], nh[3]};
    float4 o2 = {ncv[0], ncv[1], ncv[2], ncv[3]};
    *(float4*)(out + (size_t)b * 1024 + h0) = o1;
    *(float4*)(out + 4194304u + (size_t)b * 1024 + h0) = o2;
}

// ---- launch ----------------------------------------------------------------
extern "C" void kernel_launch(void* const* d_in, const int* in_sizes, int n_in,
                              void* d_out, int out_size, void* d_ws, size_t ws_size,
                              hipStream_t stream) {
    const float* input = (const float*)d_in[0];
    const float* hx    = (const float*)d_in[1];
    const float* cx    = (const float*)d_in[2];
    const float* wih   = (const float*)d_in[3];
    const float* whh   = (const float*)d_in[4];
    const float* bih   = (const float*)d_in[5];
    const float* bhh   = (const float*)d_in[6];
    const float* a1  = (const float*)d_in[7];
    const float* a3  = (const float*)d_in[8];
    const float* a4  = (const float*)d_in[9];
    const float* a5  = (const float*)d_in[10];
    const float* a6  = (const float*)d_in[11];
    const float* a7  = (const float*)d_in[12];
    const float* a8  = (const float*)d_in[13];
    const float* a9  = (const float*)d_in[14];
    const float* a10 = (const float*)d_in[15];
    const float* a11 = (const float*)d_in[16];

    char* ws = (char*)d_ws;
    signed char* A  = (signed char*)ws;                     // 32 MB
    signed char* Wt = (signed char*)(ws + 33554432);        // 8 MB
    float*       Bf = (float*)(ws + 41943040);              // 32 KB
    signed char* E  = (signed char*)(ws + 41975808);        // 128 MB

    prep_act_f<<<4096, 256, 0, stream>>>(input, a1, A, 0);
    prep_act_f<<<4096, 256, 0, stream>>>(hx, a11, A, 4);
    prep_w<<<dim3(128, 32, 2), dim3(32, 8), 0, stream>>>(wih, whh, Wt);
    prep_bias<<<32, 256, 0, stream>>>(bih, bhh, Bf);
    gemm_planes<<<dim3(32, 256), 256, 0, stream>>>(A, Wt, Bf, E);
    gates_kernel_f<<<4096, 256, 0, stream>>>(E, cx, (float*)d_out,
                                             a1, a3, a4, a5, a6, a7, a8, a9, a10, a11);
}

// Round 4
// 380.122 us; speedup vs baseline: 1.0102x; 1.0102x over previous
//
#include <hip/hip_runtime.h>
#include <cstdint>

typedef unsigned short u16;
typedef __attribute__((ext_vector_type(4))) int i32x4;

#define DEVI __device__ __forceinline__

// ---- float32 replication of reference ops (np ref computes in f32) ---------
DEVI float pactf(float x, float a) {             // literal op order, f32 CR
    float ax = fabsf(x);
    float w  = fabsf(ax - a);
    float t  = (ax - w) + a;
    float s  = (x > 0.f) ? 0.5f : ((x < 0.f) ? -0.5f : 0.0f);
    return s * t;
}
DEVI float quantf(float x, float r) {            // quant_raw value path, f32
    float xs = x / r;
    xs = fminf(fmaxf(xs, -0.9921875f), 0.9921875f);
    float e = rintf(xs * 128.0f);                // round half-even, exact
    return (e * 0.0078125f) * r;                 // e/128 exact pow2
}
// f32 transcendentals replicated via correctly-rounded f64 -> f32 rounding
// (matches round-3 verified behavior bit-for-bit; used for table build +
//  rare off-grid fallback)
DEVI float sigf(float x) {
    float eg  = (float)exp(-(double)x);          // CR f32 exp(-x)
    float den = 1.0f + eg;                       // f32 add CR
    return 1.0f / den;                           // f32 div CR
}
DEVI float tanf32(float x) { return (float)tanh((double)x); }

// Table geometry: index k = g*256 (exact for on-grid gates).
// |g| > 16.64 -> sigmoid saturates to 1.0f / quant-0; table edge 4436 is safe.
// |g| > 9.011 -> (float)tanh == +-1.0f; table edge 2309 is safe.
#define KSIG  4436
#define NSIG  8873
#define KTANH 2309
#define NTANH 4619

// ---- prep: transcendental tables (bit-identical to round-3 values) ---------
__global__ void prep_tables(float* __restrict__ Ts, float* __restrict__ Tt) {
    int i = blockIdx.x * 256 + threadIdx.x;
    if (i < NSIG)  Ts[i] = sigf((float)(i - KSIG)  * 0.00390625f);
    if (i < NTANH) Tt[i] = tanf32((float)(i - KTANH) * 0.00390625f);
}

// LUT wrappers: exact-match for on-grid inputs, f64 fallback otherwise.
DEVI float sig_lut(float g, const float* __restrict__ Ts) {
    float g256 = g * 256.0f;                     // exact for grid multiples
    float kf = rintf(g256);
    if (kf == g256) {
        if (kf >  (float)KSIG) return 1.0f;      // exact: 1+e^-x rounds to 1
        if (kf < -(float)KSIG) return 0.0f;      // downstream-quant-identical
        return Ts[(int)kf + KSIG];
    }
    return sigf(g);                              // off-grid: slow exact path
}
DEVI float tanh_lut(float g, const float* __restrict__ Tt) {
    float g256 = g * 256.0f;
    float kf = rintf(g256);
    if (kf == g256) {
        if (fabsf(kf) <= (float)KTANH) return Tt[(int)kf + KTANH];
        return copysignf(1.0f, g);               // exact: (f32)tanh == +-1
    }
    return tanf32(g);
}

// ---- prep: bitsplit activations in FLOAT32 -> int8 planes, char4-packed ----
__global__ void prep_act_f(const float* __restrict__ X, const float* __restrict__ ap,
                           signed char* __restrict__ A, int planebase) {
    int idx4 = (blockIdx.x * 256 + threadIdx.x) * 4;   // 0..4194300 step 4
    float a = ap[0];
    float4 xv4 = *(const float4*)(X + idx4);
    float v[4] = {xv4.x, xv4.y, xv4.z, xv4.w};
    signed char e4[4][4];                        // [n][elem]
#pragma unroll
    for (int el = 0; el < 4; el++) {
        float x = pactf(v[el], a) / a;           // f32 division, CR
        float xv = x;
        float beta = 1.0f;
#pragma unroll
        for (int n = 0; n < 4; n++) {
            float xs = xv / beta;                // pow2: exact
            xs = fminf(fmaxf(xs, -0.9921875f), 0.9921875f);
            float e = rintf(xs * 128.0f);        // integer in [-127,127]
            e4[n][el] = (signed char)(int)e;
            float y = e * 0.0078125f;            // e/128 exact
            xv = xv - y * beta;                  // f32 CR (product exact)
            beta = beta * 0.5f;
        }
    }
#pragma unroll
    for (int n = 0; n < 4; n++)
        *(char4*)(A + (size_t)(planebase + n) * 4194304u + idx4) =
            make_char4(e4[n][0], e4[n][1], e4[n][2], e4[n][3]);
}

// ---- prep: quantize + transpose weights -> Wt[proj][n=4096][k=1024] int8 ---
__global__ void prep_w(const float* __restrict__ W0, const float* __restrict__ W1,
                       signed char* __restrict__ Wt) {
    __shared__ float tile[32][33];
    int proj = blockIdx.z;
    const float* W = proj ? W1 : W0;             // [1024][4096] row-major
    int n0 = blockIdx.x * 32, k0 = blockIdx.y * 32;
    int tx = threadIdx.x, ty = threadIdx.y;
#pragma unroll
    for (int i = 0; i < 4; i++)
        tile[ty + i * 8][tx] = W[(size_t)(k0 + ty + i * 8) * 4096 + n0 + tx];
    __syncthreads();
#pragma unroll
    for (int i = 0; i < 4; i++) {
        float w = tile[tx][ty + i * 8];
        float xs = fminf(fmaxf(w, -0.9921875f), 0.9921875f);
        float e = rintf(xs * 128.f);             // Wq*128 integer, exact
        Wt[(size_t)proj * 4194304u + (size_t)(n0 + ty + i * 8) * 1024 + k0 + tx] =
            (signed char)(int)e;
    }
}

// ---- prep: bias integers (exact) -------------------------------------------
__global__ void prep_bias(const float* __restrict__ b0, const float* __restrict__ b1,
                          float* __restrict__ Bf) {
    int idx = blockIdx.x * 256 + threadIdx.x;    // 0..8191
    const float* b = (idx < 4096) ? b0 : b1;
    float v = b[idx & 4095];
    float xs = fminf(fmaxf(v, -0.9921875f), 0.9921875f);
    Bf[idx] = rintf(xs * 128.f);
}

// ---- main GEMM: int8 MFMA, exact i32 accumulation --------------------------
#define GLOAD16(gp, lp) __builtin_amdgcn_global_load_lds( \
    (const __attribute__((address_space(1))) void*)(gp),  \
    (__attribute__((address_space(3))) void*)(lp), 16, 0, 0)

__global__ __launch_bounds__(256) void gemm_planes(
    const signed char* __restrict__ A, const signed char* __restrict__ Wt,
    const float* __restrict__ Bf, signed char* __restrict__ E) {
    __shared__ __align__(16) signed char lds[16384]; // A tile 8KB | B tile 8KB
    int tid = threadIdx.x;
    int c0 = blockIdx.x * 128;                   // N (gate cols 0..4095)
    int r0 = blockIdx.y * 128;                   // stacked M
    int proj = (r0 >= 16384) ? 1 : 0;

    const signed char* gA = A + (size_t)(r0 + (tid >> 2)) * 1024 + (tid & 3) * 16;
    const signed char* gB = Wt + (size_t)proj * 4194304u + (size_t)(c0 + (tid >> 2)) * 1024 + (tid & 3) * 16;

    signed char* lA0 = lds + tid * 16;           // A rows 0..63
    signed char* lA1 = lds + 4096 + tid * 16;    // A rows 64..127
    signed char* lB0 = lds + 8192 + tid * 16;
    signed char* lB1 = lds + 12288 + tid * 16;

    int w = tid >> 6, l = tid & 63;
    int wm = (w >> 1) * 64, wn = (w & 1) * 64;   // wave quadrant, 64x64
    int quad = l >> 4, lrow = l & 15;

    const signed char* fA = lds + (wm + lrow) * 64 + quad * 16;
    const signed char* fB = lds + 8192 + (wn + lrow) * 64 + quad * 16;

    i32x4 acc[4][4] = {};

    for (int k0 = 0; k0 < 1024; k0 += 64) {      // 16 iterations
        GLOAD16(gA, lA0);
        GLOAD16(gA + 64 * 1024, lA1);
        GLOAD16(gB, lB0);
        GLOAD16(gB + 64 * 1024, lB1);
        gA += 64; gB += 64;
        asm volatile("s_waitcnt vmcnt(0)" ::: "memory");
        __syncthreads();
        i32x4 af[4], bfr[4];
#pragma unroll
        for (int mt = 0; mt < 4; mt++) af[mt] = *(const i32x4*)(fA + mt * 1024);
#pragma unroll
        for (int nt = 0; nt < 4; nt++) bfr[nt] = *(const i32x4*)(fB + nt * 1024);
#pragma unroll
        for (int mt = 0; mt < 4; mt++)
#pragma unroll
            for (int nt = 0; nt < 4; nt++)
                acc[mt][nt] = __builtin_amdgcn_mfma_i32_16x16x64_i8(
                    af[mt], bfr[nt], acc[mt][nt], 0, 0, 0);
        __syncthreads();
    }

    // Epilogue: int8 via LDS transpose so stores are h-contiguous coalesced.
    signed char* ctile = lds;                    // 128x128 bytes
#pragma unroll
    for (int nt = 0; nt < 4; nt++) {
        int lc = wn + nt * 16 + lrow;            // col = lane&15
        float bb = Bf[proj * 4096 + c0 + lc];
#pragma unroll
        for (int mt = 0; mt < 4; mt++) {
            int lr = wm + mt * 16 + quad * 4;    // row = quad*4+reg
#pragma unroll
            for (int r = 0; r < 4; r++) {
                float t = (float)acc[mt][nt][r] * 0.0078125f + bb;  // exact
                float tc = fminf(fmaxf(t, -127.f), 127.f);
                ctile[(lr + r) * 128 + lc] = (signed char)(int)rintf(tc);
            }
        }
    }
    __syncthreads();
#pragma unroll
    for (int p = 0; p < 4; p++) {
        int lr = (tid >> 3) + p * 32;
        int lc = (tid & 7) * 16;
        *(int4*)(E + (size_t)(r0 + lr) * 4096 + c0 + lc) =
            *(const int4*)(ctile + lr * 128 + lc);
    }
}

// ---- gates: int32 reassembly + LUT transcendentals, all-f32 exact chain ----
// OUTPUT IS FLOAT32 [2][4096][1024].
__global__ __launch_bounds__(256) void gates_kernel_t(
    const signed char* __restrict__ E, const float* __restrict__ cx,
    float* __restrict__ out,
    const float* __restrict__ TsG, const float* __restrict__ TtG,
    const float* __restrict__ a1p, const float* __restrict__ a3p,
    const float* __restrict__ a4p, const float* __restrict__ a5p,
    const float* __restrict__ a6p, const float* __restrict__ a7p,
    const float* __restrict__ a8p, const float* __restrict__ a9p,
    const float* __restrict__ a10p, const float* __restrict__ a11p) {
    __shared__ float Ts[NSIG];
    __shared__ float Tt[NTANH];
    int tid = threadIdx.x;
    for (int i = tid; i < NSIG; i += 256) Ts[i] = TsG[i];
    for (int i = tid; i < NTANH; i += 256) Tt[i] = TtG[i];
    __syncthreads();

    int b = blockIdx.x;
    int h0 = tid * 4;                            // 4 h per thread
    float a1 = a1p[0], a3 = a3p[0], a4 = a4p[0], a5 = a5p[0], a6 = a6p[0];
    float a7 = a7p[0], a8 = a8p[0], a9 = a9p[0], a10 = a10p[0], a11 = a11p[0];

    float gate[4][4];                            // [i,j,f,o][h-sub]
#pragma unroll
    for (int g = 0; g < 4; g++) {
        size_t colbase = (size_t)g * 1024 + h0;
        int s1[4] = {0, 0, 0, 0}, s2[4] = {0, 0, 0, 0};
#pragma unroll
        for (int n = 0; n < 4; n++) {
            char4 e1 = *(const char4*)(E + (((size_t)(n * 4096 + b)) << 12) + colbase);
            char4 e2 = *(const char4*)(E + (((size_t)((4 + n) * 4096 + b)) << 12) + colbase);
            int wgt = 8 >> n;                    // 8,4,2,1 == 1024*beta/128
            s1[0] += (int)e1.x * wgt; s1[1] += (int)e1.y * wgt;
            s1[2] += (int)e1.z * wgt; s1[3] += (int)e1.w * wgt;
            s2[0] += (int)e2.x * wgt; s2[1] += (int)e2.y * wgt;
            s2[2] += (int)e2.z * wgt; s2[3] += (int)e2.w * wgt;
        }
#pragma unroll
        for (int jj = 0; jj < 4; jj++) {
            // np: part = (sum of beta*e/128, exact f32) * a; sums here exact
            float p1 = ((float)s1[jj] * 0.0009765625f) * a1;   // /1024 exact
            float p2 = ((float)s2[jj] * 0.0009765625f) * a11;
            gate[g][jj] = p1 + p2;
        }
    }

    float4 cxv = *(const float4*)(cx + (size_t)b * 1024 + h0);
    float cxa[4] = {cxv.x, cxv.y, cxv.z, cxv.w};
    float nh[4], ncv[4];
#pragma unroll
    for (int jj = 0; jj < 4; jj++) {
        float gi = gate[0][jj], gj = gate[1][jj], gf = gate[2][jj], go = gate[3][jj];
        float fg  = quantf(pactf(sig_lut(gf, Ts), a3), a3);
        float ig  = quantf(pactf(sig_lut(gi, Ts), a4), a4);
        float act = quantf(pactf(tanh_lut(gj, Tt), a5), a5);
        float og  = quantf(pactf(sig_lut(go, Ts), a6), a6);
        float gc  = quantf(pactf(cxa[jj] * fg, a7), a7);
        float ai  = quantf(pactf(ig * act, a8), a8);
        float nc  = quantf(pactf(gc + ai, a9), a9);
        float ac  = quantf(pactf(tanh_lut(nc, Tt), a10), a10);
        float hh  = quantf(pactf(ac * og, a11), a11);
        nh[jj]  = hh;
        ncv[jj] = nc;
    }
    float4 o1 = {nh[0], nh[1], nh[2], nh[3]};
    float4 o2 = {ncv[0], ncv[1], ncv[2], ncv[3]};
    *(float4*)(out + (size_t)b * 1024 + h0) = o1;
    *(float4*)(out + 4194304u + (size_t)b * 1024 + h0) = o2;
}

// ---- launch ----------------------------------------------------------------
extern "C" void kernel_launch(void* const* d_in, const int* in_sizes, int n_in,
                              void* d_out, int out_size, void* d_ws, size_t ws_size,
                              hipStream_t stream) {
    const float* input = (const float*)d_in[0];
    const float* hx    = (const float*)d_in[1];
    const float* cx    = (const float*)d_in[2];
    const float* wih   = (const float*)d_in[3];
    const float* whh   = (const float*)d_in[4];
    const float* bih   = (const float*)d_in[5];
    const float* bhh   = (const float*)d_in[6];
    const float* a1  = (const float*)d_in[7];
    const float* a3  = (const float*)d_in[8];
    const float* a4  = (const float*)d_in[9];
    const float* a5  = (const float*)d_in[10];
    const float* a6  = (const float*)d_in[11];
    const float* a7  = (const float*)d_in[12];
    const float* a8  = (const float*)d_in[13];
    const float* a9  = (const float*)d_in[14];
    const float* a10 = (const float*)d_in[15];
    const float* a11 = (const float*)d_in[16];

    char* ws = (char*)d_ws;
    signed char* A  = (signed char*)ws;                     // 32 MB
    signed char* Wt = (signed char*)(ws + 33554432);        // 8 MB
    float*       Bf = (float*)(ws + 41943040);              // 32 KB
    float*       Ts = (float*)(ws + 41975808);              // 35492 B
    float*       Tt = (float*)(ws + 42011300);              // 18476 B
    signed char* E  = (signed char*)(ws + 42041344);        // 128 MB

    prep_tables<<<35, 256, 0, stream>>>(Ts, Tt);
    prep_act_f<<<4096, 256, 0, stream>>>(input, a1, A, 0);
    prep_act_f<<<4096, 256, 0, stream>>>(hx, a11, A, 4);
    prep_w<<<dim3(128, 32, 2), dim3(32, 8), 0, stream>>>(wih, whh, Wt);
    prep_bias<<<32, 256, 0, stream>>>(bih, bhh, Bf);
    gemm_planes<<<dim3(32, 256), 256, 0, stream>>>(A, Wt, Bf, E);
    gates_kernel_t<<<4096, 256, 0, stream>>>(E, cx, (float*)d_out, Ts, Tt,
                                             a1, a3, a4, a5, a6, a7, a8, a9, a10, a11);
}

// Round 6
// 374.301 us; speedup vs baseline: 1.0259x; 1.0156x over previous
//
#include <hip/hip_runtime.h>
#include <cstdint>

typedef unsigned short u16;
typedef __attribute__((ext_vector_type(4))) int i32x4;

#define DEVI __device__ __forceinline__

// ---- float32 replication of reference ops (np ref computes in f32) ---------
DEVI float pactf(float x, float a) {             // literal op order, f32 CR
    float ax = fabsf(x);
    float w  = fabsf(ax - a);
    float t  = (ax - w) + a;
    float s  = (x > 0.f) ? 0.5f : ((x < 0.f) ? -0.5f : 0.0f);
    return s * t;
}
DEVI float quantf(float x, float r) {            // quant_raw value path, f32
    float xs = x / r;
    xs = fminf(fmaxf(xs, -0.9921875f), 0.9921875f);
    float e = rintf(xs * 128.0f);                // round half-even, exact
    return (e * 0.0078125f) * r;                 // e/128 exact pow2
}
// f32 transcendentals via correctly-rounded f64 -> f32 (bit-matches np/glibc)
DEVI float sigf(float x) {
    float eg  = (float)exp(-(double)x);
    float den = 1.0f + eg;
    return 1.0f / den;
}
DEVI float tanf32(float x) { return (float)tanh((double)x); }

// Table geometry: index k = g*256 (exact for on-grid gates).
// |g| > 16.64 -> sigmoid saturates to 1.0f / quant-0; table edge 4436 safe.
// |g| > 9.011 -> (float)tanh == +-1.0f; table edge 2309 safe.
#define KSIG  4436
#define NSIG  8873
#define KTANH 2309
#define NTANH 4619

// LUT wrappers (global-memory tables; L2-resident, and most lanes saturate
// so table reads are rare). Off-grid inputs: exact f64 fallback.
DEVI float sig_lut(float g, const float* __restrict__ Ts) {
    float g256 = g * 256.0f;                     // exact for grid multiples
    float kf = rintf(g256);
    if (kf == g256) {
        if (kf >  (float)KSIG) return 1.0f;
        if (kf < -(float)KSIG) return 0.0f;
        return Ts[(int)kf + KSIG];
    }
    return sigf(g);
}
DEVI float tanh_lut(float g, const float* __restrict__ Tt) {
    float g256 = g * 256.0f;
    float kf = rintf(g256);
    if (kf == g256) {
        if (fabsf(kf) <= (float)KTANH) return Tt[(int)kf + KTANH];
        return copysignf(1.0f, g);
    }
    return tanf32(g);
}

// ---- prep: tables + bias, fused (one small launch) -------------------------
__global__ void prep_misc(const float* __restrict__ b0, const float* __restrict__ b1,
                          float* __restrict__ Bf, float* __restrict__ Ts,
                          float* __restrict__ Tt) {
    int i = blockIdx.x * 256 + threadIdx.x;
    if (i < NSIG)  Ts[i] = sigf((float)(i - KSIG)  * 0.00390625f);
    if (i < NTANH) Tt[i] = tanf32((float)(i - KTANH) * 0.00390625f);
    if (i < 8192) {
        const float* b = (i < 4096) ? b0 : b1;
        float v = b[i & 4095];
        float xs = fminf(fmaxf(v, -0.9921875f), 0.9921875f);
        Bf[i] = rintf(xs * 128.f);
    }
}

// ---- prep: bitsplit activations (input + hx fused) -> int8 planes ----------
__global__ void prep_act2(const float* __restrict__ X0, const float* __restrict__ X1,
                          const float* __restrict__ a1p, const float* __restrict__ a11p,
                          signed char* __restrict__ A) {
    int blk = blockIdx.x;
    int lo = (blk < 4096) ? 1 : 0;
    const float* X = lo ? X0 : X1;
    float a = lo ? a1p[0] : a11p[0];
    int planebase = lo ? 0 : 4;
    int idx4 = ((blk & 4095) * 256 + threadIdx.x) * 4;
    float4 xv4 = *(const float4*)(X + idx4);
    float v[4] = {xv4.x, xv4.y, xv4.z, xv4.w};
    signed char e4[4][4];                        // [n][elem]
#pragma unroll
    for (int el = 0; el < 4; el++) {
        float x = pactf(v[el], a) / a;           // f32 division, CR
        float xv = x;
        float beta = 1.0f;
#pragma unroll
        for (int n = 0; n < 4; n++) {
            float xs = xv / beta;                // pow2: exact
            xs = fminf(fmaxf(xs, -0.9921875f), 0.9921875f);
            float e = rintf(xs * 128.0f);        // integer in [-127,127]
            e4[n][el] = (signed char)(int)e;
            float y = e * 0.0078125f;            // e/128 exact
            xv = xv - y * beta;                  // f32 CR (product exact)
            beta = beta * 0.5f;
        }
    }
#pragma unroll
    for (int n = 0; n < 4; n++)
        *(char4*)(A + (size_t)(planebase + n) * 4194304u + idx4) =
            make_char4(e4[n][0], e4[n][1], e4[n][2], e4[n][3]);
}

// ---- prep: quantize + transpose weights -> Wt[proj][n=4096][k=1024] int8 ---
__global__ void prep_w(const float* __restrict__ W0, const float* __restrict__ W1,
                       signed char* __restrict__ Wt) {
    __shared__ float tile[32][33];
    int proj = blockIdx.z;
    const float* W = proj ? W1 : W0;             // [1024][4096] row-major
    int n0 = blockIdx.x * 32, k0 = blockIdx.y * 32;
    int tx = threadIdx.x, ty = threadIdx.y;
#pragma unroll
    for (int i = 0; i < 4; i++)
        tile[ty + i * 8][tx] = W[(size_t)(k0 + ty + i * 8) * 4096 + n0 + tx];
    __syncthreads();
#pragma unroll
    for (int i = 0; i < 4; i++) {
        float w = tile[tx][ty + i * 8];
        float xs = fminf(fmaxf(w, -0.9921875f), 0.9921875f);
        float e = rintf(xs * 128.f);             // Wq*128 integer, exact
        Wt[(size_t)proj * 4194304u + (size_t)(n0 + ty + i * 8) * 1024 + k0 + tx] =
            (signed char)(int)e;
    }
}

// ---- main GEMM: int8 MFMA, exact i32 accumulation, 2-phase double-buffer ---
#define GLOAD16(gp, lp) __builtin_amdgcn_global_load_lds( \
    (const __attribute__((address_space(1))) void*)(gp),  \
    (__attribute__((address_space(3))) void*)(lp), 16, 0, 0)

__global__ __launch_bounds__(256) void gemm_planes(
    const signed char* __restrict__ A, const signed char* __restrict__ Wt,
    const float* __restrict__ Bf, signed char* __restrict__ E) {
    // double-buffered: buf0 @0, buf1 @16384; each: A 8KB | B 8KB
    __shared__ __align__(16) signed char lds[32768];
    int tid = threadIdx.x;
    int c0 = blockIdx.x * 128;                   // N (gate cols 0..4095)
    int r0 = blockIdx.y * 128;                   // stacked M
    int proj = (r0 >= 16384) ? 1 : 0;

    const signed char* gA = A + (size_t)(r0 + (tid >> 2)) * 1024 + (tid & 3) * 16;
    const signed char* gB = Wt + (size_t)proj * 4194304u + (size_t)(c0 + (tid >> 2)) * 1024 + (tid & 3) * 16;

    int w = tid >> 6, l = tid & 63;
    int wm = (w >> 1) * 64, wn = (w & 1) * 64;   // wave quadrant, 64x64
    int quad = l >> 4, lrow = l & 15;

    int stoff = tid * 16;                        // per-thread staging offset
    int fAoff = (wm + lrow) * 64 + quad * 16;    // frag offsets within buffer
    int fBoff = 8192 + (wn + lrow) * 64 + quad * 16;

    i32x4 acc[4][4] = {};

#define STAGE(bufbase)                                        \
    do {                                                      \
        signed char* lb = lds + (bufbase) + stoff;            \
        GLOAD16(gA,             lb);                          \
        GLOAD16(gA + 64 * 1024, lb + 4096);                   \
        GLOAD16(gB,             lb + 8192);                   \
        GLOAD16(gB + 64 * 1024, lb + 12288);                  \
        gA += 64; gB += 64;                                   \
    } while (0)

#define COMPUTE(bufbase)                                      \
    do {                                                      \
        const signed char* fA = lds + (bufbase) + fAoff;      \
        const signed char* fB = lds + (bufbase) + fBoff;      \
        i32x4 af[4], bfr[4];                                  \
        _Pragma("unroll")                                     \
        for (int mt = 0; mt < 4; mt++) af[mt] = *(const i32x4*)(fA + mt * 1024);  \
        _Pragma("unroll")                                     \
        for (int nt = 0; nt < 4; nt++) bfr[nt] = *(const i32x4*)(fB + nt * 1024); \
        _Pragma("unroll")                                     \
        for (int mt = 0; mt < 4; mt++)                        \
            _Pragma("unroll")                                 \
            for (int nt = 0; nt < 4; nt++)                    \
                acc[mt][nt] = __builtin_amdgcn_mfma_i32_16x16x64_i8( \
                    af[mt], bfr[nt], acc[mt][nt], 0, 0, 0);   \
    } while (0)

    // prologue: stage tile 0 into buf0
    STAGE(0);
    asm volatile("s_waitcnt vmcnt(0)" ::: "memory");
    __syncthreads();

    // 16 K-steps, unrolled x2 so buffer bases are compile-time constants.
    // Per sub-step: issue next-tile stage into the OTHER buffer, compute this
    // buffer; the trailing __syncthreads (compiler auto-emits vmcnt(0)
    // lgkmcnt(0) drain) completes the prefetch and protects the buffer flip.
    for (int k0 = 0; k0 < 1024; k0 += 128) {
        STAGE(16384);                            // tile k0+64 (always exists)
        COMPUTE(0);
        __syncthreads();
        if (k0 + 128 < 1024) STAGE(0);           // tile k0+128
        COMPUTE(16384);
        __syncthreads();
    }
#undef STAGE
#undef COMPUTE

    // Epilogue: int8 via LDS transpose so stores are h-contiguous coalesced.
    signed char* ctile = lds;                    // 128x128 bytes
#pragma unroll
    for (int nt = 0; nt < 4; nt++) {
        int lc = wn + nt * 16 + lrow;            // col = lane&15
        float bb = Bf[proj * 4096 + c0 + lc];
#pragma unroll
        for (int mt = 0; mt < 4; mt++) {
            int lr = wm + mt * 16 + quad * 4;    // row = quad*4+reg
#pragma unroll
            for (int r = 0; r < 4; r++) {
                float t = (float)acc[mt][nt][r] * 0.0078125f + bb;  // exact
                float tc = fminf(fmaxf(t, -127.f), 127.f);
                ctile[(lr + r) * 128 + lc] = (signed char)(int)rintf(tc);
            }
        }
    }
    __syncthreads();
#pragma unroll
    for (int p = 0; p < 4; p++) {
        int lr = (tid >> 3) + p * 32;
        int lc = (tid & 7) * 16;
        *(int4*)(E + (size_t)(r0 + lr) * 4096 + c0 + lc) =
            *(const int4*)(ctile + lr * 128 + lc);
    }
}

// ---- gates: int32 reassembly + global-LUT transcendentals, f32 chain -------
// OUTPUT IS FLOAT32 [2][4096][1024]. No LDS, no staging, full occupancy.
__global__ __launch_bounds__(256) void gates_kernel_t(
    const signed char* __restrict__ E, const float* __restrict__ cx,
    float* __restrict__ out,
    const float* __restrict__ Ts, const float* __restrict__ Tt,
    const float* __restrict__ a1p, const float* __restrict__ a3p,
    const float* __restrict__ a4p, const float* __restrict__ a5p,
    const float* __restrict__ a6p, const float* __restrict__ a7p,
    const float* __restrict__ a8p, const float* __restrict__ a9p,
    const float* __restrict__ a10p, const float* __restrict__ a11p) {
    int tid = threadIdx.x;
    int b = blockIdx.x;
    int h0 = tid * 4;                            // 4 h per thread
    float a1 = a1p[0], a3 = a3p[0], a4 = a4p[0], a5 = a5p[0], a6 = a6p[0];
    float a7 = a7p[0], a8 = a8p[0], a9 = a9p[0], a10 = a10p[0], a11 = a11p[0];

    float gate[4][4];                            // [i,j,f,o][h-sub]
#pragma unroll
    for (int g = 0; g < 4; g++) {
        size_t colbase = (size_t)g * 1024 + h0;
        int s1[4] = {0, 0, 0, 0}, s2[4] = {0, 0, 0, 0};
#pragma unroll
        for (int n = 0; n < 4; n++) {
            char4 e1 = *(const char4*)(E + (((size_t)(n * 4096 + b)) << 12) + colbase);
            char4 e2 = *(const char4*)(E + (((size_t)((4 + n) * 4096 + b)) << 12) + colbase);
            int wgt = 8 >> n;                    // 8,4,2,1 == 1024*beta/128
            s1[0] += (int)e1.x * wgt; s1[1] += (int)e1.y * wgt;
            s1[2] += (int)e1.z * wgt; s1[3] += (int)e1.w * wgt;
            s2[0] += (int)e2.x * wgt; s2[1] += (int)e2.y * wgt;
            s2[2] += (int)e2.z * wgt; s2[3] += (int)e2.w * wgt;
        }
#pragma unroll
        for (int jj = 0; jj < 4; jj++) {
            float p1 = ((float)s1[jj] * 0.0009765625f) * a1;   // /1024 exact
            float p2 = ((float)s2[jj] * 0.0009765625f) * a11;
            gate[g][jj] = p1 + p2;
        }
    }

    float4 cxv = *(const float4*)(cx + (size_t)b * 1024 + h0);
    float cxa[4] = {cxv.x, cxv.y, cxv.z, cxv.w};
    float nh[4], ncv[4];
#pragma unroll
    for (int jj = 0; jj < 4; jj++) {
        float gi = gate[0][jj], gj = gate[1][jj], gf = gate[2][jj], go = gate[3][jj];
        float fg  = quantf(pactf(sig_lut(gf, Ts), a3), a3);
        float ig  = quantf(pactf(sig_lut(gi, Ts), a4), a4);
        float act = quantf(pactf(tanh_lut(gj, Tt), a5), a5);
        float og  = quantf(pactf(sig_lut(go, Ts), a6), a6);
        float gc  = quantf(pactf(cxa[jj] * fg, a7), a7);
        float ai  = quantf(pactf(ig * act, a8), a8);
        float nc  = quantf(pactf(gc + ai, a9), a9);
        float ac  = quantf(pactf(tanh_lut(nc, Tt), a10), a10);
        float hh  = quantf(pactf(ac * og, a11), a11);
        nh[jj]  = hh;
        ncv[jj] = nc;
    }
    float4 o1 = {nh[0], nh[1], nh[2], nh[3]};
    float4 o2 = {ncv[0], ncv[1], ncv[2], ncv[3]};
    *(float4*)(out + (size_t)b * 1024 + h0) = o1;
    *(float4*)(out + 4194304u + (size_t)b * 1024 + h0) = o2;
}

// ---- launch ----------------------------------------------------------------
extern "C" void kernel_launch(void* const* d_in, const int* in_sizes, int n_in,
                              void* d_out, int out_size, void* d_ws, size_t ws_size,
                              hipStream_t stream) {
    const float* input = (const float*)d_in[0];
    const float* hx    = (const float*)d_in[1];
    const float* cx    = (const float*)d_in[2];
    const float* wih   = (const float*)d_in[3];
    const float* whh   = (const float*)d_in[4];
    const float* bih   = (const float*)d_in[5];
    const float* bhh   = (const float*)d_in[6];
    const float* a1  = (const float*)d_in[7];
    const float* a3  = (const float*)d_in[8];
    const float* a4  = (const float*)d_in[9];
    const float* a5  = (const float*)d_in[10];
    const float* a6  = (const float*)d_in[11];
    const float* a7  = (const float*)d_in[12];
    const float* a8  = (const float*)d_in[13];
    const float* a9  = (const float*)d_in[14];
    const float* a10 = (const float*)d_in[15];
    const float* a11 = (const float*)d_in[16];

    char* ws = (char*)d_ws;
    signed char* A  = (signed char*)ws;                     // 32 MB
    signed char* Wt = (signed char*)(ws + 33554432);        // 8 MB
    float*       Bf = (float*)(ws + 41943040);              // 32 KB
    float*       Ts = (float*)(ws + 41975808);              // 35492 B
    float*       Tt = (float*)(ws + 42011300);              // 18476 B
    signed char* E  = (signed char*)(ws + 42041344);        // 128 MB

    prep_misc<<<35, 256, 0, stream>>>(bih, bhh, Bf, Ts, Tt);
    prep_act2<<<8192, 256, 0, stream>>>(input, hx, a1, a11, A);
    prep_w<<<dim3(128, 32, 2), dim3(32, 8), 0, stream>>>(wih, whh, Wt);
    gemm_planes<<<dim3(32, 256), 256, 0, stream>>>(A, Wt, Bf, E);
    gates_kernel_t<<<4096, 256, 0, stream>>>(E, cx, (float*)d_out, Ts, Tt,
                                             a1, a3, a4, a5, a6, a7, a8, a9, a10, a11);
}

// Round 7
// 373.036 us; speedup vs baseline: 1.0293x; 1.0034x over previous
//
#include <hip/hip_runtime.h>
#include <cstdint>

typedef unsigned short u16;
typedef __attribute__((ext_vector_type(4))) int i32x4;

#define DEVI __device__ __forceinline__

// ---- float32 replication of reference ops (np ref computes in f32) ---------
DEVI float pactf(float x, float a) {             // literal op order, f32 CR
    float ax = fabsf(x);
    float w  = fabsf(ax - a);
    float t  = (ax - w) + a;
    float s  = (x > 0.f) ? 0.5f : ((x < 0.f) ? -0.5f : 0.0f);
    return s * t;
}
DEVI float quantf(float x, float r) {            // quant_raw value path, f32
    float xs = x / r;
    xs = fminf(fmaxf(xs, -0.9921875f), 0.9921875f);
    float e = rintf(xs * 128.0f);                // round half-even, exact
    return (e * 0.0078125f) * r;                 // e/128 exact pow2
}
// f32 transcendentals via correctly-rounded f64 -> f32 (bit-matches np/glibc)
DEVI float sigf(float x) {
    float eg  = (float)exp(-(double)x);
    float den = 1.0f + eg;
    return 1.0f / den;
}
DEVI float tanf32(float x) { return (float)tanh((double)x); }

// Table geometry: index k = g*256 (exact for on-grid gates).
#define KSIG  4436
#define NSIG  8873
#define KTANH 2309
#define NTANH 4619

// LUT wrappers (global-memory tables; L2-resident). Off-grid: f64 fallback.
DEVI float sig_lut(float g, const float* __restrict__ Ts) {
    float g256 = g * 256.0f;                     // exact for grid multiples
    float kf = rintf(g256);
    if (kf == g256) {
        if (kf >  (float)KSIG) return 1.0f;
        if (kf < -(float)KSIG) return 0.0f;
        return Ts[(int)kf + KSIG];
    }
    return sigf(g);
}
DEVI float tanh_lut(float g, const float* __restrict__ Tt) {
    float g256 = g * 256.0f;
    float kf = rintf(g256);
    if (kf == g256) {
        if (fabsf(kf) <= (float)KTANH) return Tt[(int)kf + KTANH];
        return copysignf(1.0f, g);
    }
    return tanf32(g);
}

// ---- prep: tables + bias, fused (one small launch) -------------------------
__global__ void prep_misc(const float* __restrict__ b0, const float* __restrict__ b1,
                          float* __restrict__ Bf, float* __restrict__ Ts,
                          float* __restrict__ Tt) {
    int i = blockIdx.x * 256 + threadIdx.x;
    if (i < NSIG)  Ts[i] = sigf((float)(i - KSIG)  * 0.00390625f);
    if (i < NTANH) Tt[i] = tanf32((float)(i - KTANH) * 0.00390625f);
    if (i < 8192) {
        const float* b = (i < 4096) ? b0 : b1;
        float v = b[i & 4095];
        float xs = fminf(fmaxf(v, -0.9921875f), 0.9921875f);
        Bf[i] = rintf(xs * 128.f);
    }
}

// ---- prep: bitsplit activations (input + hx fused) -> int8 planes ----------
__global__ void prep_act2(const float* __restrict__ X0, const float* __restrict__ X1,
                          const float* __restrict__ a1p, const float* __restrict__ a11p,
                          signed char* __restrict__ A) {
    int blk = blockIdx.x;
    int lo = (blk < 4096) ? 1 : 0;
    const float* X = lo ? X0 : X1;
    float a = lo ? a1p[0] : a11p[0];
    int planebase = lo ? 0 : 4;
    int idx4 = ((blk & 4095) * 256 + threadIdx.x) * 4;
    float4 xv4 = *(const float4*)(X + idx4);
    float v[4] = {xv4.x, xv4.y, xv4.z, xv4.w};
    signed char e4[4][4];                        // [n][elem]
#pragma unroll
    for (int el = 0; el < 4; el++) {
        float x = pactf(v[el], a) / a;           // f32 division, CR
        float xv = x;
        float beta = 1.0f;
#pragma unroll
        for (int n = 0; n < 4; n++) {
            float xs = xv / beta;                // pow2: exact
            xs = fminf(fmaxf(xs, -0.9921875f), 0.9921875f);
            float e = rintf(xs * 128.0f);        // integer in [-127,127]
            e4[n][el] = (signed char)(int)e;
            float y = e * 0.0078125f;            // e/128 exact
            xv = xv - y * beta;                  // f32 CR (product exact)
            beta = beta * 0.5f;
        }
    }
#pragma unroll
    for (int n = 0; n < 4; n++)
        *(char4*)(A + (size_t)(planebase + n) * 4194304u + idx4) =
            make_char4(e4[n][0], e4[n][1], e4[n][2], e4[n][3]);
}

// ---- prep: quantize + transpose weights -> Wt[proj][n=4096][k=1024] int8 ---
__global__ void prep_w(const float* __restrict__ W0, const float* __restrict__ W1,
                       signed char* __restrict__ Wt) {
    __shared__ float tile[32][33];
    int proj = blockIdx.z;
    const float* W = proj ? W1 : W0;             // [1024][4096] row-major
    int n0 = blockIdx.x * 32, k0 = blockIdx.y * 32;
    int tx = threadIdx.x, ty = threadIdx.y;
#pragma unroll
    for (int i = 0; i < 4; i++)
        tile[ty + i * 8][tx] = W[(size_t)(k0 + ty + i * 8) * 4096 + n0 + tx];
    __syncthreads();
#pragma unroll
    for (int i = 0; i < 4; i++) {
        float w = tile[tx][ty + i * 8];
        float xs = fminf(fmaxf(w, -0.9921875f), 0.9921875f);
        float e = rintf(xs * 128.f);             // Wq*128 integer, exact
        Wt[(size_t)proj * 4194304u + (size_t)(n0 + ty + i * 8) * 1024 + k0 + tx] =
            (signed char)(int)e;
    }
}

// ---- main GEMM: int8 MFMA, 2-phase dbuf, BANK-SWIZZLED LDS -----------------
// Swizzle (both-sides, rule #21): LDS slot (row, c') holds global 16B chunk
// g = (c' - (row>>1)) & 3. Staging pre-swizzles the GLOBAL source chunk
// (LDS dest stays linear as global_load_lds requires); fragment reads use
// slot = (quad + (lrow>>1)) & 3. Spreads each 16-lane quarter-wave across
// all 32 banks (2 accesses/bank = ds_read_b128 floor) instead of 8 lanes
// piling onto one 4-bank group (64B row stride -> bank base in {0,16}).
#define GLOAD16(gp, lp) __builtin_amdgcn_global_load_lds( \
    (const __attribute__((address_space(1))) void*)(gp),  \
    (__attribute__((address_space(3))) void*)(lp), 16, 0, 0)

__global__ __launch_bounds__(256) void gemm_planes(
    const signed char* __restrict__ A, const signed char* __restrict__ Wt,
    const float* __restrict__ Bf, signed char* __restrict__ E) {
    // double-buffered: buf0 @0, buf1 @16384; each: A 8KB | B 8KB
    __shared__ __align__(16) signed char lds[32768];
    int tid = threadIdx.x;
    int c0 = blockIdx.x * 128;                   // N (gate cols 0..4095)
    int r0 = blockIdx.y * 128;                   // stacked M
    int proj = (r0 >= 16384) ? 1 : 0;

    // staging source: row = tid>>2, slot c' = tid&3 -> global chunk g
    int srow = tid >> 2;
    int g16  = (((tid & 3) + 4 - ((tid >> 3) & 3)) & 3) * 16;
    const signed char* gA = A + (size_t)(r0 + srow) * 1024 + g16;
    const signed char* gB = Wt + (size_t)proj * 4194304u + (size_t)(c0 + srow) * 1024 + g16;
    // note: +64-row staging (lb+4096 path) keeps the same g16: (row+64)>>1
    // shifts by 32 == 0 (mod 4), so the swizzle phase is identical.

    int w = tid >> 6, l = tid & 63;
    int wm = (w >> 1) * 64, wn = (w & 1) * 64;   // wave quadrant, 64x64
    int quad = l >> 4, lrow = l & 15;

    int stoff = tid * 16;                        // per-thread staging offset
    int slot  = ((quad + (lrow >> 1)) & 3) * 16; // swizzled read slot
    int fAoff = (wm + lrow) * 64 + slot;         // frag offsets within buffer
    int fBoff = 8192 + (wn + lrow) * 64 + slot;

    i32x4 acc[4][4] = {};

#define STAGE(bufbase)                                        \
    do {                                                      \
        signed char* lb = lds + (bufbase) + stoff;            \
        GLOAD16(gA,             lb);                          \
        GLOAD16(gA + 64 * 1024, lb + 4096);                   \
        GLOAD16(gB,             lb + 8192);                   \
        GLOAD16(gB + 64 * 1024, lb + 12288);                  \
        gA += 64; gB += 64;                                   \
    } while (0)

#define COMPUTE(bufbase)                                      \
    do {                                                      \
        const signed char* fA = lds + (bufbase) + fAoff;      \
        const signed char* fB = lds + (bufbase) + fBoff;      \
        i32x4 af[4], bfr[4];                                  \
        _Pragma("unroll")                                     \
        for (int mt = 0; mt < 4; mt++) af[mt] = *(const i32x4*)(fA + mt * 1024);  \
        _Pragma("unroll")                                     \
        for (int nt = 0; nt < 4; nt++) bfr[nt] = *(const i32x4*)(fB + nt * 1024); \
        _Pragma("unroll")                                     \
        for (int mt = 0; mt < 4; mt++)                        \
            _Pragma("unroll")                                 \
            for (int nt = 0; nt < 4; nt++)                    \
                acc[mt][nt] = __builtin_amdgcn_mfma_i32_16x16x64_i8( \
                    af[mt], bfr[nt], acc[mt][nt], 0, 0, 0);   \
    } while (0)

    // prologue: stage tile 0 into buf0
    STAGE(0);
    asm volatile("s_waitcnt vmcnt(0)" ::: "memory");
    __syncthreads();

    for (int k0 = 0; k0 < 1024; k0 += 128) {
        STAGE(16384);                            // tile k+1 into buf1
        COMPUTE(0);
        __syncthreads();
        if (k0 + 128 < 1024) STAGE(0);           // tile k+2 into buf0
        COMPUTE(16384);
        __syncthreads();
    }
#undef STAGE
#undef COMPUTE

    // Epilogue: int8 via LDS transpose; row stride 144 (16-aligned) breaks
    // the 4-quad same-bank aliasing of the byte writes (512B -> 576B stride).
    signed char* ctile = lds;                    // 128 x 144 bytes = 18.4KB
#pragma unroll
    for (int nt = 0; nt < 4; nt++) {
        int lc = wn + nt * 16 + lrow;            // col = lane&15
        float bb = Bf[proj * 4096 + c0 + lc];
#pragma unroll
        for (int mt = 0; mt < 4; mt++) {
            int lr = wm + mt * 16 + quad * 4;    // row = quad*4+reg
#pragma unroll
            for (int r = 0; r < 4; r++) {
                float t = (float)acc[mt][nt][r] * 0.0078125f + bb;  // exact
                float tc = fminf(fmaxf(t, -127.f), 127.f);
                ctile[(lr + r) * 144 + lc] = (signed char)(int)rintf(tc);
            }
        }
    }
    __syncthreads();
#pragma unroll
    for (int p = 0; p < 4; p++) {
        int lr = (tid >> 3) + p * 32;
        int lc = (tid & 7) * 16;
        *(int4*)(E + (size_t)(r0 + lr) * 4096 + c0 + lc) =
            *(const int4*)(ctile + lr * 144 + lc);
    }
}

// ---- gates: int32 reassembly + global-LUT transcendentals, f32 chain -------
// OUTPUT IS FLOAT32 [2][4096][1024].
__global__ __launch_bounds__(256) void gates_kernel_t(
    const signed char* __restrict__ E, const float* __restrict__ cx,
    float* __restrict__ out,
    const float* __restrict__ Ts, const float* __restrict__ Tt,
    const float* __restrict__ a1p, const float* __restrict__ a3p,
    const float* __restrict__ a4p, const float* __restrict__ a5p,
    const float* __restrict__ a6p, const float* __restrict__ a7p,
    const float* __restrict__ a8p, const float* __restrict__ a9p,
    const float* __restrict__ a10p, const float* __restrict__ a11p) {
    int tid = threadIdx.x;
    int b = blockIdx.x;
    int h0 = tid * 4;                            // 4 h per thread
    float a1 = a1p[0], a3 = a3p[0], a4 = a4p[0], a5 = a5p[0], a6 = a6p[0];
    float a7 = a7p[0], a8 = a8p[0], a9 = a9p[0], a10 = a10p[0], a11 = a11p[0];

    float gate[4][4];                            // [i,j,f,o][h-sub]
#pragma unroll
    for (int g = 0; g < 4; g++) {
        size_t colbase = (size_t)g * 1024 + h0;
        int s1[4] = {0, 0, 0, 0}, s2[4] = {0, 0, 0, 0};
#pragma unroll
        for (int n = 0; n < 4; n++) {
            char4 e1 = *(const char4*)(E + (((size_t)(n * 4096 + b)) << 12) + colbase);
            char4 e2 = *(const char4*)(E + (((size_t)((4 + n) * 4096 + b)) << 12) + colbase);
            int wgt = 8 >> n;                    // 8,4,2,1 == 1024*beta/128
            s1[0] += (int)e1.x * wgt; s1[1] += (int)e1.y * wgt;
            s1[2] += (int)e1.z * wgt; s1[3] += (int)e1.w * wgt;
            s2[0] += (int)e2.x * wgt; s2[1] += (int)e2.y * wgt;
            s2[2] += (int)e2.z * wgt; s2[3] += (int)e2.w * wgt;
        }
#pragma unroll
        for (int jj = 0; jj < 4; jj++) {
            float p1 = ((float)s1[jj] * 0.0009765625f) * a1;   // /1024 exact
            float p2 = ((float)s2[jj] * 0.0009765625f) * a11;
            gate[g][jj] = p1 + p2;
        }
    }

    float4 cxv = *(const float4*)(cx + (size_t)b * 1024 + h0);
    float cxa[4] = {cxv.x, cxv.y, cxv.z, cxv.w};
    float nh[4], ncv[4];
#pragma unroll
    for (int jj = 0; jj < 4; jj++) {
        float gi = gate[0][jj], gj = gate[1][jj], gf = gate[2][jj], go = gate[3][jj];
        float fg  = quantf(pactf(sig_lut(gf, Ts), a3), a3);
        float ig  = quantf(pactf(sig_lut(gi, Ts), a4), a4);
        float act = quantf(pactf(tanh_lut(gj, Tt), a5), a5);
        float og  = quantf(pactf(sig_lut(go, Ts), a6), a6);
        float gc  = quantf(pactf(cxa[jj] * fg, a7), a7);
        float ai  = quantf(pactf(ig * act, a8), a8);
        float nc  = quantf(pactf(gc + ai, a9), a9);
        float ac  = quantf(pactf(tanh_lut(nc, Tt), a10), a10);
        float hh  = quantf(pactf(ac * og, a11), a11);
        nh[jj]  = hh;
        ncv[jj] = nc;
    }
    float4 o1 = {nh[0], nh[1], nh[2], nh[3]};
    float4 o2 = {ncv[0], ncv[1], ncv[2], ncv[3]};
    *(float4*)(out + (size_t)b * 1024 + h0) = o1;
    *(float4*)(out + 4194304u + (size_t)b * 1024 + h0) = o2;
}

// ---- launch ----------------------------------------------------------------
extern "C" void kernel_launch(void* const* d_in, const int* in_sizes, int n_in,
                              void* d_out, int out_size, void* d_ws, size_t ws_size,
                              hipStream_t stream) {
    const float* input = (const float*)d_in[0];
    const float* hx    = (const float*)d_in[1];
    const float* cx    = (const float*)d_in[2];
    const float* wih   = (const float*)d_in[3];
    const float* whh   = (const float*)d_in[4];
    const float* bih   = (const float*)d_in[5];
    const float* bhh   = (const float*)d_in[6];
    const float* a1  = (const float*)d_in[7];
    const float* a3  = (const float*)d_in[8];
    const float* a4  = (const float*)d_in[9];
    const float* a5  = (const float*)d_in[10];
    const float* a6  = (const float*)d_in[11];
    const float* a7  = (const float*)d_in[12];
    const float* a8  = (const float*)d_in[13];
    const float* a9  = (const float*)d_in[14];
    const float* a10 = (const float*)d_in[15];
    const float* a11 = (const float*)d_in[16];

    char* ws = (char*)d_ws;
    signed char* A  = (signed char*)ws;                     // 32 MB
    signed char* Wt = (signed char*)(ws + 33554432);        // 8 MB
    float*       Bf = (float*)(ws + 41943040);              // 32 KB
    float*       Ts = (float*)(ws + 41975808);              // 35492 B
    float*       Tt = (float*)(ws + 42011300);              // 18476 B
    signed char* E  = (signed char*)(ws + 42041344);        // 128 MB

    prep_misc<<<35, 256, 0, stream>>>(bih, bhh, Bf, Ts, Tt);
    prep_act2<<<8192, 256, 0, stream>>>(input, hx, a1, a11, A);
    prep_w<<<dim3(128, 32, 2), dim3(32, 8), 0, stream>>>(wih, whh, Wt);
    gemm_planes<<<dim3(32, 256), 256, 0, stream>>>(A, Wt, Bf, E);
    gates_kernel_t<<<4096, 256, 0, stream>>>(E, cx, (float*)d_out, Ts, Tt,
                                             a1, a3, a4, a5, a6, a7, a8, a9, a10, a11);
}

// Round 8
// 334.670 us; speedup vs baseline: 1.1474x; 1.1146x over previous
//
#include <hip/hip_runtime.h>
#include <cstdint>

typedef unsigned short u16;
typedef __attribute__((ext_vector_type(4))) int i32x4;

#define DEVI __device__ __forceinline__

// ---- float32 replication of reference ops (np ref computes in f32) ---------
DEVI float pactf(float x, float a) {             // literal op order, f32 CR
    float ax = fabsf(x);
    float w  = fabsf(ax - a);
    float t  = (ax - w) + a;
    float s  = (x > 0.f) ? 0.5f : ((x < 0.f) ? -0.5f : 0.0f);
    return s * t;
}
DEVI float quantf(float x, float r) {            // quant_raw value path, f32
    float xs = x / r;
    xs = fminf(fmaxf(xs, -0.9921875f), 0.9921875f);
    float e = rintf(xs * 128.0f);                // round half-even, exact
    return (e * 0.0078125f) * r;                 // e/128 exact pow2
}
// f32 transcendentals via correctly-rounded f64 -> f32 (bit-matches np/glibc)
DEVI float sigf(float x) {
    float eg  = (float)exp(-(double)x);
    float den = 1.0f + eg;
    return 1.0f / den;
}
DEVI float tanf32(float x) { return (float)tanh((double)x); }

// Table geometry: index k = g*256 (exact for on-grid gates).
#define KSIG  4436
#define NSIG  8873
#define KTANH 2309
#define NTANH 4619

DEVI float sig_lut(float g, const float* __restrict__ Ts) {
    float g256 = g * 256.0f;                     // exact for grid multiples
    float kf = rintf(g256);
    if (kf == g256) {
        if (kf >  (float)KSIG) return 1.0f;
        if (kf < -(float)KSIG) return 0.0f;
        return Ts[(int)kf + KSIG];
    }
    return sigf(g);
}
DEVI float tanh_lut(float g, const float* __restrict__ Tt) {
    float g256 = g * 256.0f;
    float kf = rintf(g256);
    if (kf == g256) {
        if (fabsf(kf) <= (float)KTANH) return Tt[(int)kf + KTANH];
        return copysignf(1.0f, g);
    }
    return tanf32(g);
}

// ---- prep: tables + bias (REORDERED cols n' = h*4+g), fused ----------------
__global__ void prep_misc(const float* __restrict__ b0, const float* __restrict__ b1,
                          float* __restrict__ Bf, float* __restrict__ Ts,
                          float* __restrict__ Tt) {
    int i = blockIdx.x * 256 + threadIdx.x;
    if (i < NSIG)  Ts[i] = sigf((float)(i - KSIG)  * 0.00390625f);
    if (i < NTANH) Tt[i] = tanf32((float)(i - KTANH) * 0.00390625f);
    if (i < 8192) {
        int proj = i >> 12, nn = i & 4095;
        const float* b = proj ? b1 : b0;
        float v = b[nn];
        float xs = fminf(fmaxf(v, -0.9921875f), 0.9921875f);
        int np_ = ((nn & 1023) << 2) | (nn >> 10);   // h*4 + g
        Bf[proj * 4096 + np_] = rintf(xs * 128.f);
    }
}

// ---- prep: bitsplit activations (input + hx fused) -> int8 planes ----------
__global__ void prep_act2(const float* __restrict__ X0, const float* __restrict__ X1,
                          const float* __restrict__ a1p, const float* __restrict__ a11p,
                          signed char* __restrict__ A) {
    int blk = blockIdx.x;
    int lo = (blk < 4096) ? 1 : 0;
    const float* X = lo ? X0 : X1;
    float a = lo ? a1p[0] : a11p[0];
    int planebase = lo ? 0 : 4;
    int idx4 = ((blk & 4095) * 256 + threadIdx.x) * 4;
    float4 xv4 = *(const float4*)(X + idx4);
    float v[4] = {xv4.x, xv4.y, xv4.z, xv4.w};
    signed char e4[4][4];                        // [n][elem]
#pragma unroll
    for (int el = 0; el < 4; el++) {
        float x = pactf(v[el], a) / a;           // f32 division, CR
        float xv = x;
        float beta = 1.0f;
#pragma unroll
        for (int n = 0; n < 4; n++) {
            float xs = xv / beta;                // pow2: exact
            xs = fminf(fmaxf(xs, -0.9921875f), 0.9921875f);
            float e = rintf(xs * 128.0f);        // integer in [-127,127]
            e4[n][el] = (signed char)(int)e;
            float y = e * 0.0078125f;            // e/128 exact
            xv = xv - y * beta;                  // f32 CR (product exact)
            beta = beta * 0.5f;
        }
    }
#pragma unroll
    for (int n = 0; n < 4; n++)
        *(char4*)(A + (size_t)(planebase + n) * 4194304u + idx4) =
            make_char4(e4[n][0], e4[n][1], e4[n][2], e4[n][3]);
}

// ---- prep: quantize + transpose weights -> Wt[proj][n'=4096][k=1024] -------
// n' = h*4 + g (original col n = g*1024 + h): one 128-col tile of n' covers
// 32 h values x all 4 gate groups -> LSTM chain becomes block-local.
__global__ void prep_w(const float* __restrict__ W0, const float* __restrict__ W1,
                       signed char* __restrict__ Wt) {
    __shared__ float tile[32][33];
    int proj = blockIdx.z;
    const float* W = proj ? W1 : W0;             // [1024][4096] row-major
    int n0 = blockIdx.x * 32, k0 = blockIdx.y * 32;
    int tx = threadIdx.x, ty = threadIdx.y;
#pragma unroll
    for (int i = 0; i < 4; i++)
        tile[ty + i * 8][tx] = W[(size_t)(k0 + ty + i * 8) * 4096 + n0 + tx];
    __syncthreads();
#pragma unroll
    for (int i = 0; i < 4; i++) {
        int nn = n0 + ty + i * 8;
        float w = tile[tx][ty + i * 8];
        float xs = fminf(fmaxf(w, -0.9921875f), 0.9921875f);
        float e = rintf(xs * 128.f);             // Wq*128 integer, exact
        int np_ = ((nn & 1023) << 2) | (nn >> 10);
        Wt[(size_t)proj * 4194304u + (size_t)np_ * 1024 + k0 + tx] =
            (signed char)(int)e;
    }
}

// ---- FUSED main kernel: 8-plane int8 GEMM + e-quant + gates chain ----------
// Block: 128 batch x 128 n'(=32 h x 4 g), 512 threads (8 waves of 32x64).
// Loops 8 planes x 16 K-steps (2-phase dbuf, swizzled LDS); per plane folds
// acc -> e -> packed (s1 lo16 / s2 hi16, +2048 offsets; partials in (0,4096)
// so halves never interact). Epilogue: gate f32 -> LDS [128][132 dwords],
// 4-lane-group gather via b128, LUT chain, direct out writes. E eliminated.
#define GLOAD16(gp, lp) __builtin_amdgcn_global_load_lds( \
    (const __attribute__((address_space(1))) void*)(gp),  \
    (__attribute__((address_space(3))) void*)(lp), 16, 0, 0)

__global__ __launch_bounds__(512, 4) void gemm_fused(
    const signed char* __restrict__ A, const signed char* __restrict__ Wt,
    const float* __restrict__ Bf, const float* __restrict__ cx,
    float* __restrict__ out,
    const float* __restrict__ Ts, const float* __restrict__ Tt,
    const float* __restrict__ a1p, const float* __restrict__ a3p,
    const float* __restrict__ a4p, const float* __restrict__ a5p,
    const float* __restrict__ a6p, const float* __restrict__ a7p,
    const float* __restrict__ a8p, const float* __restrict__ a9p,
    const float* __restrict__ a10p, const float* __restrict__ a11p) {
    // dbuf: buf0 @0, buf1 @16384 (each A 8KB | B 8KB); epilogue gate tile
    // 128 x 528B (132 dwords, pad breaks write conflicts) reuses all 66KB.
    __shared__ __align__(16) signed char lds[67584];
    int tid = threadIdx.x;
    int c0 = blockIdx.x * 128;                   // n' tile
    int b0 = blockIdx.y * 128;                   // batch tile

    // staging: row = tid>>2, 16B chunk g16 pre-swizzled (round-7 verified)
    int srow = tid >> 2;
    int g16  = (((tid & 3) + 4 - ((tid >> 3) & 3)) & 3) * 16;
    const signed char* Ab = A + (size_t)(b0 + srow) * 1024 + g16;
    const signed char* Bb = Wt + (size_t)(c0 + srow) * 1024 + g16;

    int w = tid >> 6, l = tid & 63;
    int wm = (w >> 1) * 32, wn = (w & 1) * 64;   // wave tile 32 x 64
    int quad = l >> 4, lrow = l & 15;

    int stoff = tid * 16;
    int slot  = ((quad + (lrow >> 1)) & 3) * 16; // swizzled read slot
    int fAoff = (wm + lrow) * 64 + slot;         // + mt*1024
    int fBoff = 8192 + (wn + lrow) * 64 + slot;  // + nt*1024

    // bias (integer) for this thread's 4 columns, both projs
    float biasA[4], biasB[4];
#pragma unroll
    for (int nt = 0; nt < 4; nt++) {
        int col = c0 + wn + nt * 16 + lrow;
        biasA[nt] = Bf[col];
        biasB[nt] = Bf[4096 + col];
    }

    i32x4 acc[2][4] = {};
    i32x4 packed[2][4];
#pragma unroll
    for (int mt = 0; mt < 2; mt++)
#pragma unroll
        for (int nt = 0; nt < 4; nt++)
            packed[mt][nt] = (i32x4){0x08000800, 0x08000800, 0x08000800, 0x08000800};

#define STAGE(bufbase, ts)                                              \
    do {                                                                \
        size_t ao = ((size_t)((ts) >> 4) << 22) + (size_t)(((ts) & 15) << 6); \
        size_t bo = (((ts) >= 64) ? (size_t)4194304u : 0) + (size_t)(((ts) & 15) << 6); \
        signed char* lb = lds + (bufbase) + stoff;                      \
        GLOAD16(Ab + ao, lb);                                           \
        GLOAD16(Bb + bo, lb + 8192);                                    \
    } while (0)

#define COMPUTE(bufbase)                                                \
    do {                                                                \
        const signed char* fA = lds + (bufbase) + fAoff;                \
        const signed char* fB = lds + (bufbase) + fBoff;                \
        i32x4 af[2], bfr[4];                                            \
        _Pragma("unroll")                                               \
        for (int mt = 0; mt < 2; mt++) af[mt] = *(const i32x4*)(fA + mt * 1024); \
        _Pragma("unroll")                                               \
        for (int nt = 0; nt < 4; nt++) bfr[nt] = *(const i32x4*)(fB + nt * 1024); \
        _Pragma("unroll")                                               \
        for (int mt = 0; mt < 2; mt++)                                  \
            _Pragma("unroll")                                           \
            for (int nt = 0; nt < 4; nt++)                              \
                acc[mt][nt] = __builtin_amdgcn_mfma_i32_16x16x64_i8(    \
                    af[mt], bfr[nt], acc[mt][nt], 0, 0, 0);             \
    } while (0)

#define FOLD(plane)                                                     \
    do {                                                                \
        int wgt = 8 >> ((plane) & 3);                                   \
        int mulw = ((plane) < 4) ? wgt : (wgt << 16);                   \
        _Pragma("unroll")                                               \
        for (int mt = 0; mt < 2; mt++)                                  \
            _Pragma("unroll")                                           \
            for (int nt = 0; nt < 4; nt++) {                            \
                float bb = ((plane) < 4) ? biasA[nt] : biasB[nt];       \
                _Pragma("unroll")                                       \
                for (int r = 0; r < 4; r++) {                           \
                    float t = (float)acc[mt][nt][r] * 0.0078125f + bb;  \
                    float tc = fminf(fmaxf(t, -127.f), 127.f);          \
                    packed[mt][nt][r] += mulw * (int)rintf(tc);         \
                    acc[mt][nt][r] = 0;                                 \
                }                                                       \
            }                                                           \
    } while (0)

    // prologue: stage step 0 into buf0
    STAGE(0, 0);
    asm volatile("s_waitcnt vmcnt(0)" ::: "memory");
    __syncthreads();

    // 128 flat K-steps (8 planes x 16), 2 per iteration
    for (int it = 0; it < 64; ++it) {
        STAGE(16384, 2 * it + 1);
        COMPUTE(0);
        __syncthreads();
        if (it < 63) STAGE(0, 2 * it + 2);
        COMPUTE(16384);
        if ((it & 7) == 7) FOLD(it >> 3);        // plane ends at t=16p+15
        __syncthreads();
    }
#undef STAGE
#undef COMPUTE
#undef FOLD

    // ---- epilogue: gates -> LDS, 4-lane gather, LSTM chain, store ----------
    float a1v = a1p[0], a11v = a11p[0];
#pragma unroll
    for (int mt = 0; mt < 2; mt++)
#pragma unroll
        for (int nt = 0; nt < 4; nt++)
#pragma unroll
            for (int r = 0; r < 4; r++) {
                int row = wm + mt * 16 + quad * 4 + r;
                int col = wn + nt * 16 + lrow;
                int pk = packed[mt][nt][r];
                int s1 = (pk & 0xFFFF) - 2048;
                int s2 = (pk >> 16) - 2048;
                float gate = ((float)s1 * 0.0009765625f) * a1v +
                             ((float)s2 * 0.0009765625f) * a11v;
                *(float*)(lds + row * 528 + col * 4) = gate;
            }
    __syncthreads();

    float a3 = a3p[0], a4 = a4p[0], a5 = a5p[0], a6 = a6p[0], a7 = a7p[0];
    float a8 = a8p[0], a9 = a9p[0], a10 = a10p[0], a11 = a11p[0];

    int row = tid >> 2;                          // 128 rows
    int hc  = (tid & 3) * 8;                     // local h base (0..31)
    size_t obase = (size_t)(b0 + row) * 1024 + (c0 >> 2) + hc;
    float4 cx0 = *(const float4*)(cx + obase);
    float4 cx1 = *(const float4*)(cx + obase + 4);
    float cxa[8] = {cx0.x, cx0.y, cx0.z, cx0.w, cx1.x, cx1.y, cx1.z, cx1.w};
    float nh[8], ncv[8];
#pragma unroll
    for (int j = 0; j < 8; j++) {
        float4 g4 = *(const float4*)(lds + row * 528 + (hc + j) * 16);
        float gi = g4.x, gj = g4.y, gf = g4.z, go = g4.w;
        float fg  = quantf(pactf(sig_lut(gf, Ts), a3), a3);
        float ig  = quantf(pactf(sig_lut(gi, Ts), a4), a4);
        float act = quantf(pactf(tanh_lut(gj, Tt), a5), a5);
        float og  = quantf(pactf(sig_lut(go, Ts), a6), a6);
        float gc  = quantf(pactf(cxa[j] * fg, a7), a7);
        float ai  = quantf(pactf(ig * act, a8), a8);
        float nc  = quantf(pactf(gc + ai, a9), a9);
        float ac  = quantf(pactf(tanh_lut(nc, Tt), a10), a10);
        float hh  = quantf(pactf(ac * og, a11), a11);
        nh[j]  = hh;
        ncv[j] = nc;
    }
    *(float4*)(out + obase)                 = (float4){nh[0], nh[1], nh[2], nh[3]};
    *(float4*)(out + obase + 4)             = (float4){nh[4], nh[5], nh[6], nh[7]};
    *(float4*)(out + 4194304u + obase)      = (float4){ncv[0], ncv[1], ncv[2], ncv[3]};
    *(float4*)(out + 4194304u + obase + 4)  = (float4){ncv[4], ncv[5], ncv[6], ncv[7]};
}

// ---- launch ----------------------------------------------------------------
extern "C" void kernel_launch(void* const* d_in, const int* in_sizes, int n_in,
                              void* d_out, int out_size, void* d_ws, size_t ws_size,
                              hipStream_t stream) {
    const float* input = (const float*)d_in[0];
    const float* hx    = (const float*)d_in[1];
    const float* cx    = (const float*)d_in[2];
    const float* wih   = (const float*)d_in[3];
    const float* whh   = (const float*)d_in[4];
    const float* bih   = (const float*)d_in[5];
    const float* bhh   = (const float*)d_in[6];
    const float* a1  = (const float*)d_in[7];
    const float* a3  = (const float*)d_in[8];
    const float* a4  = (const float*)d_in[9];
    const float* a5  = (const float*)d_in[10];
    const float* a6  = (const float*)d_in[11];
    const float* a7  = (const float*)d_in[12];
    const float* a8  = (const float*)d_in[13];
    const float* a9  = (const float*)d_in[14];
    const float* a10 = (const float*)d_in[15];
    const float* a11 = (const float*)d_in[16];

    char* ws = (char*)d_ws;
    signed char* A  = (signed char*)ws;                     // 32 MB
    signed char* Wt = (signed char*)(ws + 33554432);        // 8 MB
    float*       Bf = (float*)(ws + 41943040);              // 32 KB
    float*       Ts = (float*)(ws + 41975808);              // 35492 B
    float*       Tt = (float*)(ws + 42011300);              // 18476 B

    prep_misc<<<35, 256, 0, stream>>>(bih, bhh, Bf, Ts, Tt);
    prep_act2<<<8192, 256, 0, stream>>>(input, hx, a1, a11, A);
    prep_w<<<dim3(128, 32, 2), dim3(32, 8), 0, stream>>>(wih, whh, Wt);
    gemm_fused<<<dim3(32, 32), 512, 0, stream>>>(A, Wt, Bf, cx, (float*)d_out,
                                                 Ts, Tt, a1, a3, a4, a5, a6,
                                                 a7, a8, a9, a10, a11);
}